// Round 15
// baseline (499.604 us; speedup 1.0000x reference)
//
#include <hip/hip_runtime.h>

typedef unsigned short u16;
typedef short bf16x8 __attribute__((ext_vector_type(8)));
typedef unsigned short u16x8 __attribute__((ext_vector_type(8)));
typedef unsigned short u16x4 __attribute__((ext_vector_type(4)));
typedef float f32x4 __attribute__((ext_vector_type(4)));

typedef __attribute__((address_space(1))) void* gas_ptr;
typedef __attribute__((address_space(3))) void* las_ptr;

__device__ __forceinline__ float bf2f(u16 v) {
  unsigned u = ((unsigned)v) << 16;
  return __builtin_bit_cast(float, u);
}
__device__ __forceinline__ u16 f2bf(float f) {
  unsigned u = __builtin_bit_cast(unsigned, f);
  u += 0x7fffu + ((u >> 16) & 1u);
  return (u16)(u >> 16);
}
__device__ __forceinline__ f32x4 mfma16(bf16x8 a, bf16x8 b, f32x4 c) {
  return __builtin_amdgcn_mfma_f32_16x16x32_bf16(a, b, c, 0, 0, 0);
}
__device__ __forceinline__ void gload_lds16(const void* g, void* l) {
  __builtin_amdgcn_global_load_lds((gas_ptr)g, (las_ptr)l, 16, 0, 0);
}

#define SB __builtin_amdgcn_sched_barrier(0)
#define BAR do { SB; __builtin_amdgcn_s_barrier(); SB; } while (0)

// ------ fused: gt = logsigmoid(x@Wgt)/16 AND xb = bf16(x); 4 tokens/block ------
__global__ __launch_bounds__(256) void k_gtcast(const float* __restrict__ x,
                                                const float* __restrict__ Wgt,
                                                u16* __restrict__ xb,
                                                float* __restrict__ gt) {
  int t0 = blockIdx.x * 4;
  int tid = threadIdx.x;
  __shared__ __align__(16) float xs[4][2048];
#pragma unroll
  for (int tok = 0; tok < 4; ++tok) {
    size_t rb = (size_t)(t0 + tok) * 2048;
#pragma unroll
    for (int i = 0; i < 8; ++i) {
      int idx = tid + i * 256;
      float v = x[rb + idx];
      xs[tok][idx] = v;
      xb[rb + idx] = f2bf(v);
    }
  }
  __syncthreads();
  int head = tid & 15, ks = tid >> 4;
  float p0 = 0.f, p1 = 0.f, p2 = 0.f, p3 = 0.f;
  for (int i = 0; i < 128; ++i) {
    int k = ks + i * 16;
    float wv = Wgt[k * 16 + head];
    p0 += xs[0][k] * wv;
    p1 += xs[1][k] * wv;
    p2 += xs[2][k] * wv;
    p3 += xs[3][k] * wv;
  }
  __shared__ float ps[4][16][17];
  ps[0][ks][head] = p0;
  ps[1][ks][head] = p1;
  ps[2][ks][head] = p2;
  ps[3][ks][head] = p3;
  __syncthreads();
  if (tid < 64) {
    int tok = tid >> 4, hh = tid & 15;
    float z = 0.f;
#pragma unroll
    for (int j = 0; j < 16; ++j) z += ps[tok][j][hh];
    float lsz = (z >= 0.f) ? -log1pf(__expf(-z)) : (z - log1pf(__expf(z)));
    int t = t0 + tok;
    int b = t >> 12, tl = t & 4095;
    gt[((size_t)(b * 16 + hh)) * 4096 + tl] = lsz * 0.0625f;
  }
}

// ------ weight transpose+cast, 5 matrices in one launch (dest contiguous) ------
__global__ __launch_bounds__(256) void k_wtrans5(const float* __restrict__ W0,
                                                 const float* __restrict__ W1,
                                                 const float* __restrict__ W2,
                                                 const float* __restrict__ W3,
                                                 const float* __restrict__ W4,
                                                 u16* __restrict__ WT) {
  const int K = 2048, N = 2048;
  int z = blockIdx.z;
  const float* W = (z == 0) ? W0 : (z == 1) ? W1 : (z == 2) ? W2 : (z == 3) ? W3 : W4;
  u16* dst = WT + (size_t)z * 4194304;
  int n0 = blockIdx.x * 64, k0 = blockIdx.y * 64;
  int tid = threadIdx.x;
  __shared__ __align__(16) float tf[64][68];
  int r = tid >> 4, c4 = (tid & 15) * 4;
#pragma unroll
  for (int i = 0; i < 4; ++i) {
    int row = r + i * 16;
    f32x4 v = *(const f32x4*)(W + (size_t)(k0 + row) * N + n0 + c4);
    *(f32x4*)&tf[row][c4] = v;
  }
  __syncthreads();
#pragma unroll
  for (int i = 0; i < 2; ++i) {
    int chunk = tid + i * 256;
    int nl = chunk >> 3, c8 = (chunk & 7) * 8;
    u16x8 o;
#pragma unroll
    for (int m = 0; m < 8; ++m) o[m] = f2bf(tf[c8 + m][nl]);
    *(u16x8*)(dst + (size_t)(n0 + nl) * K + k0 + c8) = o;
  }
}

// ============ 256x256 GEMM, read-pipelined 4-phase (best R6 schedule) ============
// MODE 1: f32 out row-stride N.
// MODE 2: bf16 out split into 4 [M][2048] bufs by col>>11; RoPE fused for bufs 0,1
//         with cos/sin staged into the dead Al/Bl LDS post-K-loop (XOR-swizzled, conflict-free).
template <int MODE>
__global__ __launch_bounds__(512, 2) void k_gemm2(const u16* __restrict__ A,
                                                  const u16* __restrict__ Bt,
                                                  void* __restrict__ Cp, int M, int N, int K,
                                                  const float* __restrict__ cosT,
                                                  const float* __restrict__ sinT) {
  __shared__ __align__(16) u16 Al[2][2][8192];  // [buf][half][128*64] st_16x32-swizzled
  __shared__ __align__(16) u16 Bl[2][2][8192];
  int tid = threadIdx.x, w = tid >> 6, lane = tid & 63, l15 = lane & 15, l4 = lane >> 4;
  int wm = w >> 2, wn = w & 3;
  // bijective XCD swizzle + 4x4 supertile walk (needs nwg%8==0, nbx%4==0, nby%4==0)
  int nwg = gridDim.x, bid = blockIdx.x;
  int q8 = nwg >> 3;
  int wg = (bid & 7) * q8 + (bid >> 3);
  int nbx = N >> 8;
  int nstx = nbx >> 2;
  int st = wg >> 4, r16 = wg & 15;
  int sm = st / nstx, sn = st - sm * nstx;
  int m0 = ((sm << 2) + (r16 >> 2)) << 8;
  int n0 = ((sn << 2) + (r16 & 3)) << 8;
  // staging coords: linear LDS slot -> (r,c) via inverse st_16x32 swizzle
  int rA0, rA1, rB0, rB1, cc0, cc1;
  {
    int rr[2], cch[2];
#pragma unroll
    for (int q = 0; q < 2; ++q) {
      int L = (q * 512 + tid) * 16;
      int sub = L >> 10, inner = L & 1023;
      inner ^= ((inner >> 9) & 1) << 5;
      rr[q] = ((sub >> 1) << 4) + (inner >> 6);
      cch[q] = ((sub & 1) << 5) + ((inner & 63) >> 1);
    }
    rA0 = ((rr[0] >> 6) << 7) + (rr[0] & 63);
    rA1 = ((rr[1] >> 6) << 7) + (rr[1] & 63);
    rB0 = ((rr[0] >> 5) << 6) + (rr[0] & 31);
    rB1 = ((rr[1] >> 5) << 6) + (rr[1] & 31);
    cc0 = cch[0]; cc1 = cch[1];
  }
  int innerA = ((l15 << 6) + (l4 << 4)) ^ ((l15 & 8) << 2);  // swizzled read offset (bytes)
  int ldsW = w << 9;  // wave-uniform element base for staging (q=0)

#define STAGE_A(t, h)                                                                   \
  do {                                                                                  \
    int b_ = (t) & 1;                                                                   \
    gload_lds16(A + (size_t)(m0 + rA0 + (h) * 64) * K + (t) * 64 + cc0, &Al[b_][h][ldsW]); \
    gload_lds16(A + (size_t)(m0 + rA1 + (h) * 64) * K + (t) * 64 + cc1, &Al[b_][h][4096 + ldsW]); \
  } while (0)
#define STAGE_B(t, h)                                                                   \
  do {                                                                                  \
    int b_ = (t) & 1;                                                                   \
    gload_lds16(Bt + (size_t)(n0 + rB0 + (h) * 32) * K + (t) * 64 + cc0, &Bl[b_][h][ldsW]); \
    gload_lds16(Bt + (size_t)(n0 + rB1 + (h) * 32) * K + (t) * 64 + cc1, &Bl[b_][h][4096 + ldsW]); \
  } while (0)

  const f32x4 z4 = {0.f, 0.f, 0.f, 0.f};
  f32x4 acc[8][4];
#pragma unroll
  for (int i = 0; i < 8; ++i)
#pragma unroll
    for (int j = 0; j < 4; ++j) acc[i][j] = z4;
  // four independent fragment register sets (pipelined one phase ahead)
  bf16x8 af0[4][2], af1[4][2], bf0[2][2], bf1[2][2];

#define LDA0(buf)                                                                        \
  do {                                                                                   \
    const char* Ab = (const char*)&Al[buf][0][0];                                        \
    _Pragma("unroll") for (int fi = 0; fi < 4; ++fi) _Pragma("unroll") for (int ks = 0; ks < 2; ++ks) \
        af0[fi][ks] = *(const bf16x8*)(Ab + (((wm * 4 + fi) * 2 + ks) << 10) + innerA);  \
  } while (0)
#define LDA1(buf)                                                                        \
  do {                                                                                   \
    const char* Ab = (const char*)&Al[buf][1][0];                                        \
    _Pragma("unroll") for (int fi = 0; fi < 4; ++fi) _Pragma("unroll") for (int ks = 0; ks < 2; ++ks) \
        af1[fi][ks] = *(const bf16x8*)(Ab + (((wm * 4 + fi) * 2 + ks) << 10) + innerA);  \
  } while (0)
#define LDB0(buf)                                                                        \
  do {                                                                                   \
    const char* Bb = (const char*)&Bl[buf][0][0];                                        \
    _Pragma("unroll") for (int fj = 0; fj < 2; ++fj) _Pragma("unroll") for (int ks = 0; ks < 2; ++ks) \
        bf0[fj][ks] = *(const bf16x8*)(Bb + (((wn * 2 + fj) * 2 + ks) << 10) + innerA);  \
  } while (0)
#define LDB1(buf)                                                                        \
  do {                                                                                   \
    const char* Bb = (const char*)&Bl[buf][1][0];                                        \
    _Pragma("unroll") for (int fj = 0; fj < 2; ++fj) _Pragma("unroll") for (int ks = 0; ks < 2; ++ks) \
        bf1[fj][ks] = *(const bf16x8*)(Bb + (((wn * 2 + fj) * 2 + ks) << 10) + innerA);  \
  } while (0)
#define MM(hm, hn, AF, BF)                                                               \
  do {                                                                                   \
    __builtin_amdgcn_s_setprio(1);                                                       \
    _Pragma("unroll") for (int fi = 0; fi < 4; ++fi) _Pragma("unroll") for (int fj = 0; fj < 2; ++fj) \
        _Pragma("unroll") for (int ks = 0; ks < 2; ++ks)                                 \
            acc[(hm) * 4 + fi][(hn) * 2 + fj] =                                          \
                mfma16(AF[fi][ks], BF[fj][ks], acc[(hm) * 4 + fi][(hn) * 2 + fj]);       \
    __builtin_amdgcn_s_setprio(0);                                                       \
  } while (0)

  int nt = K >> 6;
  // prologue: stage tile0 (both halves) + tile1 h0; land tile0; preload h0 frags.
  STAGE_A(0, 0); STAGE_B(0, 0); STAGE_A(0, 1); STAGE_B(0, 1);
  if (nt > 1) {
    STAGE_A(1, 0); STAGE_B(1, 0);
    asm volatile("s_waitcnt vmcnt(4)" ::: "memory");
  } else {
    asm volatile("s_waitcnt vmcnt(0)" ::: "memory");
  }
  SB;
  BAR;
  LDA0(0); LDB0(0);  // 12 ds_reads; retired by t=0 P1's lgkmcnt(4)
  // Pipeline invariants (audited steady + t=0 + tails) — the R6 best schedule:
  //  P1 lgkm(4): keeps bf1's 4 reads, retires prev-P4/prologue 12
  //  P2 lgkm(8): keeps af1's 8, retires bf1's 4
  //  P3 lgkm(0): retires af1; ONE vmcnt gate/tile keeps 3 newest stage-pairs
  //  P4: no waits; reads next-tile h0 frags after the gate+BAR
  for (int t = 0; t < nt; ++t) {
    int cur = t & 1, nxt = cur ^ 1;
    // P1: MFMA(0,0) = af0 x bf0; read bf1; stage B(t+1,h1)
    LDB1(cur);
    if (t + 1 < nt) STAGE_B(t + 1, 1);
    asm volatile("s_waitcnt lgkmcnt(4)" ::: "memory"); SB;
    MM(0, 0, af0, bf0);
    BAR;
    // P2: MFMA(0,1) = af0 x bf1; read af1; stage A(t+1,h1)
    LDA1(cur);
    if (t + 1 < nt) STAGE_A(t + 1, 1);
    asm volatile("s_waitcnt lgkmcnt(8)" ::: "memory"); SB;
    MM(0, 1, af0, bf1);
    BAR;
    // P3: MFMA(1,0) = af1 x bf0; stage A(t+2,h0); per-tile vmcnt gate
    if (t + 2 < nt) STAGE_A(t + 2, 0);
    asm volatile("s_waitcnt lgkmcnt(0)" ::: "memory"); SB;
    MM(1, 0, af1, bf0);
    if (t + 1 < nt) {
      if (t + 2 < nt) { asm volatile("s_waitcnt vmcnt(6)" ::: "memory"); }
      else            { asm volatile("s_waitcnt vmcnt(4)" ::: "memory"); }
    } else            { asm volatile("s_waitcnt vmcnt(0)" ::: "memory"); }
    SB;
    BAR;
    // P4: MFMA(1,1) = af1 x bf1; read next-tile h0 frags; stage B(t+2,h0); NO waits
    if (t + 1 < nt) { LDA0(nxt); LDB0(nxt); }
    if (t + 2 < nt) STAGE_B(t + 2, 0);
    MM(1, 1, af1, bf1);
    BAR;
  }
  asm volatile("s_waitcnt lgkmcnt(0)" ::: "memory");
  asm volatile("s_waitcnt vmcnt(0)" ::: "memory");  // drain DMAs before LDS reuse
#undef STAGE_A
#undef STAGE_B
#undef LDA0
#undef LDA1
#undef LDB0
#undef LDB1
#undef MM
  // ---- epilogue ----
  if (MODE == 2) {
    // Reuse dead Al/Bl as cos/sin row cache: rows tl0..tl0+255, 64 f32 each,
    // column XOR-swizzled by ((row&7)<<3): spreads the 4 l4-group rows across
    // distinct banks (conflict-free reads); f32x4 writes stay contiguous
    // (XOR only touches bits >=3 and is constant over a 4-float span).
    float* cosL = (float*)&Al[0][0][0];  // 64 KB = 256*64 f32
    float* sinL = (float*)&Bl[0][0][0];
    __syncthreads();  // all waves done reading Al/Bl (per-wave lgkm drained above)
    int tl0 = m0 & 4095;
#pragma unroll
    for (int i = 0; i < 8; ++i) {
      int idx = tid + i * 512;  // [0,4096) f32x4 chunks
      int rr_ = idx >> 4, c4_ = (idx & 15) * 4;
      int c4s = c4_ ^ ((rr_ & 7) << 3);
      *(f32x4*)&cosL[rr_ * 64 + c4s] = *(const f32x4*)(cosT + (size_t)(tl0 + rr_) * 64 + c4_);
      *(f32x4*)&sinL[rr_ * 64 + c4s] = *(const f32x4*)(sinT + (size_t)(tl0 + rr_) * 64 + c4_);
    }
    __syncthreads();
#pragma unroll
    for (int fi = 0; fi < 8; ++fi)
#pragma unroll
      for (int fj = 0; fj < 4; ++fj) {
        int rloc = wm * 128 + fi * 16 + l4 * 4;
        int row0 = m0 + rloc;
        int col = n0 + wn * 64 + fj * 16 + l15;
        int bufi = col >> 11;
        u16* C = (u16*)Cp + (size_t)bufi * 16777216 + (col & 2047);
        if (bufi < 2) {  // q or k: interleaved RoPE from LDS tables (wave-uniform branch)
          int i0 = (col & 127) >> 1;
          bool evenc = (col & 1) == 0;
#pragma unroll
          for (int reg = 0; reg < 4; ++reg) {
            int rr_ = rloc + reg;
            int iswz = i0 ^ ((rr_ & 7) << 3);
            float cv = cosL[rr_ * 64 + iswz];
            float sv = sinL[rr_ * 64 + iswz];
            float v = acc[fi][fj][reg];
            float partner = __shfl_xor(v, 1);
            float r = evenc ? (v * cv - partner * sv) : (partner * sv + v * cv);
            C[(size_t)(row0 + reg) * 2048] = f2bf(r);
          }
        } else {
#pragma unroll
          for (int reg = 0; reg < 4; ++reg) C[(size_t)(row0 + reg) * 2048] = f2bf(acc[fi][fj][reg]);
        }
      }
  } else {
#pragma unroll
    for (int fi = 0; fi < 8; ++fi)
#pragma unroll
      for (int fj = 0; fj < 4; ++fj) {
        int row0 = m0 + wm * 128 + fi * 16 + l4 * 4;
        int col = n0 + wn * 64 + fj * 16 + l15;
        float* C = (float*)Cp;
#pragma unroll
        for (int reg = 0; reg < 4; ++reg) C[(size_t)(row0 + reg) * N + col] = acc[fi][fj][reg];
      }
  }
}

// ---------------- per-chunk inclusive cumsum over 256 ----------------
__global__ void k_cumsum(const float* __restrict__ gt, float* __restrict__ gcum) {
  int n = blockIdx.x, bh = blockIdx.y, c = threadIdx.x;
  __shared__ float s[256];
  size_t base = (size_t)bh * 4096 + n * 256;
  s[c] = gt[base + c];
  __syncthreads();
  for (int off = 1; off < 256; off <<= 1) {
    float t = (c >= off) ? s[c - off] : 0.f;
    __syncthreads();
    s[c] += t;
    __syncthreads();
  }
  gcum[base + c] = s[c];
}

// ---------------- S_in^T[e][d] = sum_c (k[c,d]*kdec[c]*scale) * v[c,e], per (bh,n) ----------------
__global__ __launch_bounds__(256) void k_sin(const u16* __restrict__ kb, const u16* __restrict__ vb,
                                             const float* __restrict__ gcum, float* __restrict__ SinT) {
  int n = blockIdx.x, bh = blockIdx.y;
  int b = bh >> 4, h = bh & 15;
  int tid = threadIdx.x, w = tid >> 6, lane = tid & 63, l15 = lane & 15, l4 = lane >> 4;
  size_t t0 = (size_t)b * 4096 + n * 256;
  __shared__ float gc[256];
  __shared__ __align__(16) u16 kt[128 * 72];
  __shared__ __align__(16) u16 vt[128 * 72];
  gc[tid] = gcum[(size_t)bh * 4096 + n * 256 + tid];
  __syncthreads();
  float gtot = gc[255];
  const float scale = 0.08838834764831845f;
  const f32x4 z4 = {0.f, 0.f, 0.f, 0.f};
  f32x4 acc[2][8];
#pragma unroll
  for (int i = 0; i < 2; ++i)
#pragma unroll
    for (int j = 0; j < 8; ++j) acc[i][j] = z4;
  int cl = tid >> 2, fq = (tid & 3) * 32;
  for (int c0 = 0; c0 < 256; c0 += 64) {
    __syncthreads();
    float kd = __expf(gtot - gc[c0 + cl]) * scale;
    const u16* kp = kb + (t0 + c0 + cl) * 2048 + h * 128 + fq;
    const u16* vp = vb + (t0 + c0 + cl) * 2048 + h * 128 + fq;
#pragma unroll
    for (int jj = 0; jj < 4; ++jj) {
      u16x8 kv = *(const u16x8*)(kp + jj * 8);
      u16x8 vv = *(const u16x8*)(vp + jj * 8);
#pragma unroll
      for (int m = 0; m < 8; ++m) {
        int f = fq + jj * 8 + m;
        kt[f * 72 + cl] = f2bf(bf2f(kv[m]) * kd);
        vt[f * 72 + cl] = vv[m];
      }
    }
    __syncthreads();
#pragma unroll
    for (int ks = 0; ks < 2; ++ks) {
      int coff = ks * 32 + l4 * 8;
      bf16x8 bfr[8];
#pragma unroll
      for (int bc = 0; bc < 8; ++bc) bfr[bc] = *(const bf16x8*)(vt + (bc * 16 + l15) * 72 + coff);
#pragma unroll
      for (int ar = 0; ar < 2; ++ar) {
        bf16x8 afr = *(const bf16x8*)(kt + (w * 32 + ar * 16 + l15) * 72 + coff);
#pragma unroll
        for (int bc = 0; bc < 8; ++bc) acc[ar][bc] = mfma16(afr, bfr[bc], acc[ar][bc]);
      }
    }
  }
  size_t sbo = ((size_t)bh * 16 + n) * 16384;
#pragma unroll
  for (int ar = 0; ar < 2; ++ar) {
    int d = w * 32 + ar * 16 + l4 * 4;
#pragma unroll
    for (int bc = 0; bc < 8; ++bc) {
      int e = bc * 16 + l15;
      *(f32x4*)(SinT + sbo + (size_t)e * 128 + d) = acc[ar][bc];
    }
  }
}

// ---------------- recurrence: S_T[bh,n] (bf16, [e][d]) = state before chunk n ----------------
__global__ void k_state(const float* __restrict__ SinT, const float* __restrict__ gcum,
                        u16* __restrict__ S_T) {
  int bh = blockIdx.x >> 3, sl = blockIdx.x & 7;
  int base_l = sl * 2048 + threadIdx.x;
  float S[8];
#pragma unroll
  for (int i = 0; i < 8; ++i) S[i] = 0.f;
  for (int nn = 0; nn < 16; ++nn) {
    size_t tb = ((size_t)bh * 16 + nn) * 16384;
#pragma unroll
    for (int i = 0; i < 8; ++i) S_T[tb + base_l + i * 256] = f2bf(S[i]);
    float cd = __expf(gcum[(size_t)bh * 4096 + nn * 256 + 255]);
#pragma unroll
    for (int i = 0; i < 8; ++i) S[i] = S[i] * cd + SinT[tb + base_l + i * 256];
  }
}

// ---------------- fused attention: balanced 8-wave version ----------------
__global__ __launch_bounds__(512, 4) void k_attn(
    const u16* __restrict__ qb, const u16* __restrict__ kb, const u16* __restrict__ vb,
    const u16* __restrict__ gbuf, const float* __restrict__ gcum,
    const u16* __restrict__ S_T, u16* __restrict__ ob) {
  int n = blockIdx.x, bh = blockIdx.y;
  int b = bh >> 4, h = bh & 15;
  int tid = threadIdx.x, w = tid >> 6, lane = tid & 63, l15 = lane & 15, l4 = lane >> 4;
  size_t t0 = (size_t)b * 4096 + n * 256;
  __shared__ float gc[256];
  __shared__ __align__(16) u16 vt[32768];   // V^T[e][s], idx ^ ((e&7)<<3)
  __shared__ __align__(16) u16 Pb[8][512];  // per-wave P[16][32], idx ^ ((r&3)<<3)
  if (tid < 256) gc[tid] = gcum[(size_t)bh * 4096 + n * 256 + tid];
  {
    int s = tid & 255, e0 = (tid >> 8) * 64;
    const u16* vp = vb + (t0 + s) * 2048 + h * 128 + e0;
#pragma unroll
    for (int j = 0; j < 8; ++j) {
      u16x8 vv = *(const u16x8*)(vp + j * 8);
#pragma unroll
      for (int m = 0; m < 8; ++m) {
        int e = e0 + j * 8 + m;
        vt[(e * 256 + s) ^ ((e & 7) << 3)] = vv[m];
      }
    }
  }
  __syncthreads();
  const float scale = 0.08838834764831845f;
  u16* P = Pb[w];
  const f32x4 z4 = {0.f, 0.f, 0.f, 0.f};
  f32x4 acc[2][8];
#pragma unroll
  for (int i = 0; i < 2; ++i)
#pragma unroll
    for (int j = 0; j < 8; ++j) acc[i][j] = z4;
  int r0s[2], nsbs[2];
  r0s[0] = w * 16;        nsbs[0] = (w + 2) >> 1;
  r0s[1] = (15 - w) * 16; nsbs[1] = 8 - (w >> 1);
#pragma unroll
  for (int rb = 0; rb < 2; ++rb) {
    int r0 = r0s[rb], nsb = nsbs[rb];
    bf16x8 qa[4];
    {
      const u16* qp = qb + (t0 + r0 + l15) * 2048 + h * 128 + l4 * 8;
#pragma unroll
      for (int ks = 0; ks < 4; ++ks) qa[ks] = *(const bf16x8*)(qp + ks * 32);
    }
    for (int sbk = 0; sbk < nsb; ++sbk) {
      int s0 = sbk * 32;
      f32x4 sc[2] = {z4, z4};
#pragma unroll
      for (int cf = 0; cf < 2; ++cf) {
        const u16* kp = kb + (t0 + s0 + cf * 16 + l15) * 2048 + h * 128 + l4 * 8;
#pragma unroll
        for (int ks = 0; ks < 4; ++ks)
          sc[cf] = mfma16(qa[ks], *(const bf16x8*)(kp + ks * 32), sc[cf]);
      }
#pragma unroll
      for (int cf = 0; cf < 2; ++cf) {
        int s = s0 + cf * 16 + l15;
        float gs = gc[s];
#pragma unroll
        for (int reg = 0; reg < 4; ++reg) {
          int rl = l4 * 4 + reg;
          int r = r0 + rl;
          float val = (r >= s) ? sc[cf][reg] * scale * __expf(gc[r] - gs) : 0.f;
          P[(rl * 32 + cf * 16 + l15) ^ ((rl & 3) << 3)] = f2bf(val);
        }
      }
      bf16x8 pa = *(const bf16x8*)(P + ((l15 * 32 + l4 * 8) ^ ((l15 & 3) << 3)));
#pragma unroll
      for (int bc = 0; bc < 8; ++bc) {
        int e = bc * 16 + l15;
        bf16x8 vf = *(const bf16x8*)(vt + ((e * 256 + s0 + l4 * 8) ^ ((e & 7) << 3)));
        acc[rb][bc] = mfma16(pa, vf, acc[rb][bc]);
      }
    }
  }
  size_t sbase = ((size_t)bh * 16 + n) * 16384;
#pragma unroll
  for (int rb = 0; rb < 2; ++rb) {
    int r0 = r0s[rb];
    float qd = __expf(gc[r0 + l15]);
#pragma unroll
    for (int ks = 0; ks < 4; ++ks) {
      u16x8 qu = *(const u16x8*)(qb + (t0 + r0 + l15) * 2048 + h * 128 + ks * 32 + l4 * 8);
      u16x8 ru;
#pragma unroll
      for (int m = 0; m < 8; ++m) ru[m] = f2bf(bf2f(qu[m]) * qd);
      bf16x8 pa2 = __builtin_bit_cast(bf16x8, ru);
#pragma unroll
      for (int bc = 0; bc < 8; ++bc) {
        int e = bc * 16 + l15;
        bf16x8 sf = *(const bf16x8*)(S_T + sbase + (size_t)e * 128 + ks * 32 + l4 * 8);
        acc[rb][bc] = mfma16(pa2, sf, acc[rb][bc]);
      }
    }
  }
#pragma unroll
  for (int rb = 0; rb < 2; ++rb) {
    int r0 = r0s[rb];
#pragma unroll
    for (int reg = 0; reg < 4; ++reg) {
      float ss = 0.f;
#pragma unroll
      for (int bc = 0; bc < 8; ++bc) { float v = acc[rb][bc][reg]; ss += v * v; }
      ss += __shfl_xor(ss, 1);
      ss += __shfl_xor(ss, 2);
      ss += __shfl_xor(ss, 4);
      ss += __shfl_xor(ss, 8);
      float rinv = rsqrtf(ss * 0.0078125f + 1e-5f);
      int r = r0 + l4 * 4 + reg;
      size_t rowoff = (t0 + r) * 2048 + h * 128;
#pragma unroll
      for (int bc = 0; bc < 8; ++bc) {
        int e = bc * 16 + l15;
        float gval = bf2f(gbuf[rowoff + e]);
        float sig = 1.f / (1.f + __expf(-gval));
        ob[rowoff + e] = f2bf(acc[rb][bc][reg] * rinv * gval * sig);
      }
    }
  }
}

extern "C" void kernel_launch(void* const* d_in, const int* in_sizes, int n_in,
                              void* d_out, int out_size, void* d_ws, size_t ws_size,
                              hipStream_t stream) {
  const float* x    = (const float*)d_in[0];
  const float* cosT = (const float*)d_in[1];
  const float* sinT = (const float*)d_in[2];
  const float* Wq   = (const float*)d_in[3];
  const float* Wk   = (const float*)d_in[4];
  const float* Wv   = (const float*)d_in[5];
  const float* Wg   = (const float*)d_in[6];
  const float* Wgt  = (const float*)d_in[7];
  const float* Wout = (const float*)d_in[8];
  float* out = (float*)d_out;

  const size_t MB32 = (size_t)33554432;
  const size_t W8   = (size_t)8388608;
  char* ws = (char*)d_ws;
  size_t need = MB32 + 5 * W8 + 4 * MB32 + 2 * (size_t)524288;
  if (ws_size < need) return;

  u16*   xb    = (u16*)(ws);
  float* SinT  = (float*)(ws);
  u16*   ob    = (u16*)(ws);
  u16*   WqT   = (u16*)(ws + MB32);          // WqT..WgT,WoutT contiguous (5x 2048^2 bf16)
  u16*   S_T   = (u16*)(ws + MB32);          // overlays WqT+WkT after projections
  u16*   WoutT = (u16*)(ws + MB32 + 4 * W8);
  u16*   qb    = (u16*)(ws + MB32 + 5 * W8); // qb,kb,vb,gb contiguous 4x32MB
  u16*   kb    = qb + 16777216;
  u16*   vb    = qb + 2 * 16777216;
  u16*   gb    = qb + 3 * (size_t)16777216;
  float* gt    = (float*)(ws + MB32 + 5 * W8 + 4 * MB32);
  float* gcum  = (float*)(ws + MB32 + 5 * W8 + 4 * MB32 + 524288);

  k_gtcast<<<2048, 256, 0, stream>>>(x, Wgt, xb, gt);
  k_wtrans5<<<dim3(32, 32, 5), 256, 0, stream>>>(Wq, Wk, Wv, Wg, Wout, WqT);

  // fused q/k/v/g projection with RoPE fused into the epilogue for q,k
  k_gemm2<2><<<1024, 512, 0, stream>>>(xb, WqT, qb, 8192, 8192, 2048, cosT, sinT);

  k_cumsum<<<dim3(16, 32), 256, 0, stream>>>(gt, gcum);
  k_sin<<<dim3(16, 32), 256, 0, stream>>>(kb, vb, gcum, SinT);
  k_state<<<256, 256, 0, stream>>>(SinT, gcum, S_T);
  k_attn<<<dim3(16, 32), 512, 0, stream>>>(qb, kb, vb, gb, gcum, S_T, ob);
  k_gemm2<1><<<256, 512, 0, stream>>>(ob, WoutT, out, 8192, 2048, 2048, nullptr, nullptr);
}

// Round 16
// 493.594 us; speedup vs baseline: 1.0122x; 1.0122x over previous
//
#include <hip/hip_runtime.h>

typedef unsigned short u16;
typedef short bf16x8 __attribute__((ext_vector_type(8)));
typedef unsigned short u16x8 __attribute__((ext_vector_type(8)));
typedef unsigned short u16x4 __attribute__((ext_vector_type(4)));
typedef float f32x4 __attribute__((ext_vector_type(4)));

typedef __attribute__((address_space(1))) void* gas_ptr;
typedef __attribute__((address_space(3))) void* las_ptr;

__device__ __forceinline__ float bf2f(u16 v) {
  unsigned u = ((unsigned)v) << 16;
  return __builtin_bit_cast(float, u);
}
__device__ __forceinline__ u16 f2bf(float f) {
  unsigned u = __builtin_bit_cast(unsigned, f);
  u += 0x7fffu + ((u >> 16) & 1u);
  return (u16)(u >> 16);
}
__device__ __forceinline__ f32x4 mfma16(bf16x8 a, bf16x8 b, f32x4 c) {
  return __builtin_amdgcn_mfma_f32_16x16x32_bf16(a, b, c, 0, 0, 0);
}
__device__ __forceinline__ void gload_lds16(const void* g, void* l) {
  __builtin_amdgcn_global_load_lds((gas_ptr)g, (las_ptr)l, 16, 0, 0);
}

#define SB __builtin_amdgcn_sched_barrier(0)
#define BAR do { SB; __builtin_amdgcn_s_barrier(); SB; } while (0)

// ------ fused: gt = logsigmoid(x@Wgt)/16 AND xb = bf16(x); 4 tokens/block ------
__global__ __launch_bounds__(256) void k_gtcast(const float* __restrict__ x,
                                                const float* __restrict__ Wgt,
                                                u16* __restrict__ xb,
                                                float* __restrict__ gt) {
  int t0 = blockIdx.x * 4;
  int tid = threadIdx.x;
  __shared__ __align__(16) float xs[4][2048];
#pragma unroll
  for (int tok = 0; tok < 4; ++tok) {
    size_t rb = (size_t)(t0 + tok) * 2048;
#pragma unroll
    for (int i = 0; i < 8; ++i) {
      int idx = tid + i * 256;
      float v = x[rb + idx];
      xs[tok][idx] = v;
      xb[rb + idx] = f2bf(v);
    }
  }
  __syncthreads();
  int head = tid & 15, ks = tid >> 4;
  float p0 = 0.f, p1 = 0.f, p2 = 0.f, p3 = 0.f;
  for (int i = 0; i < 128; ++i) {
    int k = ks + i * 16;
    float wv = Wgt[k * 16 + head];
    p0 += xs[0][k] * wv;
    p1 += xs[1][k] * wv;
    p2 += xs[2][k] * wv;
    p3 += xs[3][k] * wv;
  }
  __shared__ float ps[4][16][17];
  ps[0][ks][head] = p0;
  ps[1][ks][head] = p1;
  ps[2][ks][head] = p2;
  ps[3][ks][head] = p3;
  __syncthreads();
  if (tid < 64) {
    int tok = tid >> 4, hh = tid & 15;
    float z = 0.f;
#pragma unroll
    for (int j = 0; j < 16; ++j) z += ps[tok][j][hh];
    float lsz = (z >= 0.f) ? -log1pf(__expf(-z)) : (z - log1pf(__expf(z)));
    int t = t0 + tok;
    int b = t >> 12, tl = t & 4095;
    gt[((size_t)(b * 16 + hh)) * 4096 + tl] = lsz * 0.0625f;
  }
}

// ------ weight transpose+cast, 5 matrices in one launch (dest contiguous) ------
__global__ __launch_bounds__(256) void k_wtrans5(const float* __restrict__ W0,
                                                 const float* __restrict__ W1,
                                                 const float* __restrict__ W2,
                                                 const float* __restrict__ W3,
                                                 const float* __restrict__ W4,
                                                 u16* __restrict__ WT) {
  const int K = 2048, N = 2048;
  int z = blockIdx.z;
  const float* W = (z == 0) ? W0 : (z == 1) ? W1 : (z == 2) ? W2 : (z == 3) ? W3 : W4;
  u16* dst = WT + (size_t)z * 4194304;
  int n0 = blockIdx.x * 64, k0 = blockIdx.y * 64;
  int tid = threadIdx.x;
  __shared__ __align__(16) float tf[64][68];
  int r = tid >> 4, c4 = (tid & 15) * 4;
#pragma unroll
  for (int i = 0; i < 4; ++i) {
    int row = r + i * 16;
    f32x4 v = *(const f32x4*)(W + (size_t)(k0 + row) * N + n0 + c4);
    *(f32x4*)&tf[row][c4] = v;
  }
  __syncthreads();
#pragma unroll
  for (int i = 0; i < 2; ++i) {
    int chunk = tid + i * 256;
    int nl = chunk >> 3, c8 = (chunk & 7) * 8;
    u16x8 o;
#pragma unroll
    for (int m = 0; m < 8; ++m) o[m] = f2bf(tf[c8 + m][nl]);
    *(u16x8*)(dst + (size_t)(n0 + nl) * K + k0 + c8) = o;
  }
}

// ============ 256x256 GEMM, read-pipelined 4-phase (best R6 schedule) ============
// MODE 1: f32 out row-stride N.
// MODE 2: bf16 out split into 4 [M][2048] bufs by col>>11; RoPE fused for bufs 0,1
//         with cos/sin staged into the dead Al/Bl LDS post-K-loop.
template <int MODE>
__global__ __launch_bounds__(512, 2) void k_gemm2(const u16* __restrict__ A,
                                                  const u16* __restrict__ Bt,
                                                  void* __restrict__ Cp, int M, int N, int K,
                                                  const float* __restrict__ cosT,
                                                  const float* __restrict__ sinT) {
  __shared__ __align__(16) u16 Al[2][2][8192];  // [buf][half][128*64] st_16x32-swizzled
  __shared__ __align__(16) u16 Bl[2][2][8192];
  int tid = threadIdx.x, w = tid >> 6, lane = tid & 63, l15 = lane & 15, l4 = lane >> 4;
  int wm = w >> 2, wn = w & 3;
  // bijective XCD swizzle + 4x4 supertile walk (needs nwg%8==0, nbx%4==0, nby%4==0)
  int nwg = gridDim.x, bid = blockIdx.x;
  int q8 = nwg >> 3;
  int wg = (bid & 7) * q8 + (bid >> 3);
  int nbx = N >> 8;
  int nstx = nbx >> 2;
  int st = wg >> 4, r16 = wg & 15;
  int sm = st / nstx, sn = st - sm * nstx;
  int m0 = ((sm << 2) + (r16 >> 2)) << 8;
  int n0 = ((sn << 2) + (r16 & 3)) << 8;
  // staging coords: linear LDS slot -> (r,c) via inverse st_16x32 swizzle
  int rA0, rA1, rB0, rB1, cc0, cc1;
  {
    int rr[2], cch[2];
#pragma unroll
    for (int q = 0; q < 2; ++q) {
      int L = (q * 512 + tid) * 16;
      int sub = L >> 10, inner = L & 1023;
      inner ^= ((inner >> 9) & 1) << 5;
      rr[q] = ((sub >> 1) << 4) + (inner >> 6);
      cch[q] = ((sub & 1) << 5) + ((inner & 63) >> 1);
    }
    rA0 = ((rr[0] >> 6) << 7) + (rr[0] & 63);
    rA1 = ((rr[1] >> 6) << 7) + (rr[1] & 63);
    rB0 = ((rr[0] >> 5) << 6) + (rr[0] & 31);
    rB1 = ((rr[1] >> 5) << 6) + (rr[1] & 31);
    cc0 = cch[0]; cc1 = cch[1];
  }
  int innerA = ((l15 << 6) + (l4 << 4)) ^ ((l15 & 8) << 2);  // swizzled read offset (bytes)
  int ldsW = w << 9;  // wave-uniform element base for staging (q=0)

#define STAGE_A(t, h)                                                                   \
  do {                                                                                  \
    int b_ = (t) & 1;                                                                   \
    gload_lds16(A + (size_t)(m0 + rA0 + (h) * 64) * K + (t) * 64 + cc0, &Al[b_][h][ldsW]); \
    gload_lds16(A + (size_t)(m0 + rA1 + (h) * 64) * K + (t) * 64 + cc1, &Al[b_][h][4096 + ldsW]); \
  } while (0)
#define STAGE_B(t, h)                                                                   \
  do {                                                                                  \
    int b_ = (t) & 1;                                                                   \
    gload_lds16(Bt + (size_t)(n0 + rB0 + (h) * 32) * K + (t) * 64 + cc0, &Bl[b_][h][ldsW]); \
    gload_lds16(Bt + (size_t)(n0 + rB1 + (h) * 32) * K + (t) * 64 + cc1, &Bl[b_][h][4096 + ldsW]); \
  } while (0)

  const f32x4 z4 = {0.f, 0.f, 0.f, 0.f};
  f32x4 acc[8][4];
#pragma unroll
  for (int i = 0; i < 8; ++i)
#pragma unroll
    for (int j = 0; j < 4; ++j) acc[i][j] = z4;
  // four independent fragment register sets (pipelined one phase ahead)
  bf16x8 af0[4][2], af1[4][2], bf0[2][2], bf1[2][2];

#define LDA0(buf)                                                                        \
  do {                                                                                   \
    const char* Ab = (const char*)&Al[buf][0][0];                                        \
    _Pragma("unroll") for (int fi = 0; fi < 4; ++fi) _Pragma("unroll") for (int ks = 0; ks < 2; ++ks) \
        af0[fi][ks] = *(const bf16x8*)(Ab + (((wm * 4 + fi) * 2 + ks) << 10) + innerA);  \
  } while (0)
#define LDA1(buf)                                                                        \
  do {                                                                                   \
    const char* Ab = (const char*)&Al[buf][1][0];                                        \
    _Pragma("unroll") for (int fi = 0; fi < 4; ++fi) _Pragma("unroll") for (int ks = 0; ks < 2; ++ks) \
        af1[fi][ks] = *(const bf16x8*)(Ab + (((wm * 4 + fi) * 2 + ks) << 10) + innerA);  \
  } while (0)
#define LDB0(buf)                                                                        \
  do {                                                                                   \
    const char* Bb = (const char*)&Bl[buf][0][0];                                        \
    _Pragma("unroll") for (int fj = 0; fj < 2; ++fj) _Pragma("unroll") for (int ks = 0; ks < 2; ++ks) \
        bf0[fj][ks] = *(const bf16x8*)(Bb + (((wn * 2 + fj) * 2 + ks) << 10) + innerA);  \
  } while (0)
#define LDB1(buf)                                                                        \
  do {                                                                                   \
    const char* Bb = (const char*)&Bl[buf][1][0];                                        \
    _Pragma("unroll") for (int fj = 0; fj < 2; ++fj) _Pragma("unroll") for (int ks = 0; ks < 2; ++ks) \
        bf1[fj][ks] = *(const bf16x8*)(Bb + (((wn * 2 + fj) * 2 + ks) << 10) + innerA);  \
  } while (0)
#define MM(hm, hn, AF, BF)                                                               \
  do {                                                                                   \
    __builtin_amdgcn_s_setprio(1);                                                       \
    _Pragma("unroll") for (int fi = 0; fi < 4; ++fi) _Pragma("unroll") for (int fj = 0; fj < 2; ++fj) \
        _Pragma("unroll") for (int ks = 0; ks < 2; ++ks)                                 \
            acc[(hm) * 4 + fi][(hn) * 2 + fj] =                                          \
                mfma16(AF[fi][ks], BF[fj][ks], acc[(hm) * 4 + fi][(hn) * 2 + fj]);       \
    __builtin_amdgcn_s_setprio(0);                                                       \
  } while (0)

  int nt = K >> 6;
  // prologue: stage tile0 (both halves) + tile1 h0; land tile0; preload h0 frags.
  STAGE_A(0, 0); STAGE_B(0, 0); STAGE_A(0, 1); STAGE_B(0, 1);
  if (nt > 1) {
    STAGE_A(1, 0); STAGE_B(1, 0);
    asm volatile("s_waitcnt vmcnt(4)" ::: "memory");
  } else {
    asm volatile("s_waitcnt vmcnt(0)" ::: "memory");
  }
  SB;
  BAR;
  LDA0(0); LDB0(0);  // 12 ds_reads; retired by t=0 P1's lgkmcnt(4)
  // Pipeline invariants (audited steady + t=0 + tails) — the R6 best schedule:
  //  P1 lgkm(4): keeps bf1's 4 reads, retires prev-P4/prologue 12
  //  P2 lgkm(8): keeps af1's 8, retires bf1's 4
  //  P3 lgkm(0): retires af1; ONE vmcnt gate/tile keeps 3 newest stage-pairs
  //  P4: no waits; reads next-tile h0 frags after the gate+BAR
  for (int t = 0; t < nt; ++t) {
    int cur = t & 1, nxt = cur ^ 1;
    // P1: MFMA(0,0) = af0 x bf0; read bf1; stage B(t+1,h1)
    LDB1(cur);
    if (t + 1 < nt) STAGE_B(t + 1, 1);
    asm volatile("s_waitcnt lgkmcnt(4)" ::: "memory"); SB;
    MM(0, 0, af0, bf0);
    BAR;
    // P2: MFMA(0,1) = af0 x bf1; read af1; stage A(t+1,h1)
    LDA1(cur);
    if (t + 1 < nt) STAGE_A(t + 1, 1);
    asm volatile("s_waitcnt lgkmcnt(8)" ::: "memory"); SB;
    MM(0, 1, af0, bf1);
    BAR;
    // P3: MFMA(1,0) = af1 x bf0; stage A(t+2,h0); per-tile vmcnt gate
    if (t + 2 < nt) STAGE_A(t + 2, 0);
    asm volatile("s_waitcnt lgkmcnt(0)" ::: "memory"); SB;
    MM(1, 0, af1, bf0);
    if (t + 1 < nt) {
      if (t + 2 < nt) { asm volatile("s_waitcnt vmcnt(6)" ::: "memory"); }
      else            { asm volatile("s_waitcnt vmcnt(4)" ::: "memory"); }
    } else            { asm volatile("s_waitcnt vmcnt(0)" ::: "memory"); }
    SB;
    BAR;
    // P4: MFMA(1,1) = af1 x bf1; read next-tile h0 frags; stage B(t+2,h0); NO waits
    if (t + 1 < nt) { LDA0(nxt); LDB0(nxt); }
    if (t + 2 < nt) STAGE_B(t + 2, 0);
    MM(1, 1, af1, bf1);
    BAR;
  }
  asm volatile("s_waitcnt lgkmcnt(0)" ::: "memory");
  asm volatile("s_waitcnt vmcnt(0)" ::: "memory");  // drain DMAs before LDS reuse
#undef STAGE_A
#undef STAGE_B
#undef LDA0
#undef LDA1
#undef LDB0
#undef LDB1
#undef MM
  // ---- epilogue ----
  if (MODE == 2) {
    // Reuse dead Al/Bl as cos/sin row cache: rows tl0..tl0+255, 64 f32 each.
    // (4096 % 256 == 0 so a 256-row tile never straddles the batch boundary.)
    float* cosL = (float*)&Al[0][0][0];  // 64 KB = 256*64 f32
    float* sinL = (float*)&Bl[0][0][0];
    __syncthreads();  // all waves done reading Al/Bl (per-wave lgkm drained above)
    int tl0 = m0 & 4095;
#pragma unroll
    for (int i = 0; i < 8; ++i) {
      int idx = tid + i * 512;  // [0,4096) f32x4 chunks
      int rr_ = idx >> 4, c4_ = (idx & 15) * 4;
      *(f32x4*)&cosL[rr_ * 64 + c4_] = *(const f32x4*)(cosT + (size_t)(tl0 + rr_) * 64 + c4_);
      *(f32x4*)&sinL[rr_ * 64 + c4_] = *(const f32x4*)(sinT + (size_t)(tl0 + rr_) * 64 + c4_);
    }
    __syncthreads();
#pragma unroll
    for (int fi = 0; fi < 8; ++fi)
#pragma unroll
      for (int fj = 0; fj < 4; ++fj) {
        int rloc = wm * 128 + fi * 16 + l4 * 4;
        int row0 = m0 + rloc;
        int col = n0 + wn * 64 + fj * 16 + l15;
        int bufi = col >> 11;
        u16* C = (u16*)Cp + (size_t)bufi * 16777216 + (col & 2047);
        if (bufi < 2) {  // q or k: interleaved RoPE from LDS tables (wave-uniform branch)
          int i0 = (col & 127) >> 1;
          bool evenc = (col & 1) == 0;
#pragma unroll
          for (int reg = 0; reg < 4; ++reg) {
            float cv = cosL[(rloc + reg) * 64 + i0];
            float sv = sinL[(rloc + reg) * 64 + i0];
            float v = acc[fi][fj][reg];
            float partner = __shfl_xor(v, 1);
            float r = evenc ? (v * cv - partner * sv) : (partner * sv + v * cv);
            C[(size_t)(row0 + reg) * 2048] = f2bf(r);
          }
        } else {
#pragma unroll
          for (int reg = 0; reg < 4; ++reg) C[(size_t)(row0 + reg) * 2048] = f2bf(acc[fi][fj][reg]);
        }
      }
  } else {
#pragma unroll
    for (int fi = 0; fi < 8; ++fi)
#pragma unroll
      for (int fj = 0; fj < 4; ++fj) {
        int row0 = m0 + wm * 128 + fi * 16 + l4 * 4;
        int col = n0 + wn * 64 + fj * 16 + l15;
        float* C = (float*)Cp;
#pragma unroll
        for (int reg = 0; reg < 4; ++reg) C[(size_t)(row0 + reg) * N + col] = acc[fi][fj][reg];
      }
  }
}

// ---------------- per-chunk inclusive cumsum over 256 ----------------
__global__ void k_cumsum(const float* __restrict__ gt, float* __restrict__ gcum) {
  int n = blockIdx.x, bh = blockIdx.y, c = threadIdx.x;
  __shared__ float s[256];
  size_t base = (size_t)bh * 4096 + n * 256;
  s[c] = gt[base + c];
  __syncthreads();
  for (int off = 1; off < 256; off <<= 1) {
    float t = (c >= off) ? s[c - off] : 0.f;
    __syncthreads();
    s[c] += t;
    __syncthreads();
  }
  gcum[base + c] = s[c];
}

// ---------------- S_in^T[e][d] = sum_c (k[c,d]*kdec[c]*scale) * v[c,e], per (bh,n) ----------------
__global__ __launch_bounds__(256) void k_sin(const u16* __restrict__ kb, const u16* __restrict__ vb,
                                             const float* __restrict__ gcum, float* __restrict__ SinT) {
  int n = blockIdx.x, bh = blockIdx.y;
  int b = bh >> 4, h = bh & 15;
  int tid = threadIdx.x, w = tid >> 6, lane = tid & 63, l15 = lane & 15, l4 = lane >> 4;
  size_t t0 = (size_t)b * 4096 + n * 256;
  __shared__ float gc[256];
  __shared__ __align__(16) u16 kt[128 * 72];
  __shared__ __align__(16) u16 vt[128 * 72];
  gc[tid] = gcum[(size_t)bh * 4096 + n * 256 + tid];
  __syncthreads();
  float gtot = gc[255];
  const float scale = 0.08838834764831845f;
  const f32x4 z4 = {0.f, 0.f, 0.f, 0.f};
  f32x4 acc[2][8];
#pragma unroll
  for (int i = 0; i < 2; ++i)
#pragma unroll
    for (int j = 0; j < 8; ++j) acc[i][j] = z4;
  int cl = tid >> 2, fq = (tid & 3) * 32;
  for (int c0 = 0; c0 < 256; c0 += 64) {
    __syncthreads();
    float kd = __expf(gtot - gc[c0 + cl]) * scale;
    const u16* kp = kb + (t0 + c0 + cl) * 2048 + h * 128 + fq;
    const u16* vp = vb + (t0 + c0 + cl) * 2048 + h * 128 + fq;
#pragma unroll
    for (int jj = 0; jj < 4; ++jj) {
      u16x8 kv = *(const u16x8*)(kp + jj * 8);
      u16x8 vv = *(const u16x8*)(vp + jj * 8);
#pragma unroll
      for (int m = 0; m < 8; ++m) {
        int f = fq + jj * 8 + m;
        kt[f * 72 + cl] = f2bf(bf2f(kv[m]) * kd);
        vt[f * 72 + cl] = vv[m];
      }
    }
    __syncthreads();
#pragma unroll
    for (int ks = 0; ks < 2; ++ks) {
      int coff = ks * 32 + l4 * 8;
      bf16x8 bfr[8];
#pragma unroll
      for (int bc = 0; bc < 8; ++bc) bfr[bc] = *(const bf16x8*)(vt + (bc * 16 + l15) * 72 + coff);
#pragma unroll
      for (int ar = 0; ar < 2; ++ar) {
        bf16x8 afr = *(const bf16x8*)(kt + (w * 32 + ar * 16 + l15) * 72 + coff);
#pragma unroll
        for (int bc = 0; bc < 8; ++bc) acc[ar][bc] = mfma16(afr, bfr[bc], acc[ar][bc]);
      }
    }
  }
  size_t sbo = ((size_t)bh * 16 + n) * 16384;
#pragma unroll
  for (int ar = 0; ar < 2; ++ar) {
    int d = w * 32 + ar * 16 + l4 * 4;
#pragma unroll
    for (int bc = 0; bc < 8; ++bc) {
      int e = bc * 16 + l15;
      *(f32x4*)(SinT + sbo + (size_t)e * 128 + d) = acc[ar][bc];
    }
  }
}

// ---------------- recurrence: S_T[bh,n] (bf16, [e][d]) = state before chunk n ----------------
__global__ void k_state(const float* __restrict__ SinT, const float* __restrict__ gcum,
                        u16* __restrict__ S_T) {
  int bh = blockIdx.x >> 3, sl = blockIdx.x & 7;
  int base_l = sl * 2048 + threadIdx.x;
  float S[8];
#pragma unroll
  for (int i = 0; i < 8; ++i) S[i] = 0.f;
  for (int nn = 0; nn < 16; ++nn) {
    size_t tb = ((size_t)bh * 16 + nn) * 16384;
#pragma unroll
    for (int i = 0; i < 8; ++i) S_T[tb + base_l + i * 256] = f2bf(S[i]);
    float cd = __expf(gcum[(size_t)bh * 4096 + nn * 256 + 255]);
#pragma unroll
    for (int i = 0; i < 8; ++i) S[i] = S[i] * cd + SinT[tb + base_l + i * 256];
  }
}

// ---------------- fused attention: balanced 8-wave version ----------------
__global__ __launch_bounds__(512, 4) void k_attn(
    const u16* __restrict__ qb, const u16* __restrict__ kb, const u16* __restrict__ vb,
    const u16* __restrict__ gbuf, const float* __restrict__ gcum,
    const u16* __restrict__ S_T, u16* __restrict__ ob) {
  int n = blockIdx.x, bh = blockIdx.y;
  int b = bh >> 4, h = bh & 15;
  int tid = threadIdx.x, w = tid >> 6, lane = tid & 63, l15 = lane & 15, l4 = lane >> 4;
  size_t t0 = (size_t)b * 4096 + n * 256;
  __shared__ float gc[256];
  __shared__ __align__(16) u16 vt[32768];   // V^T[e][s], idx ^ ((e&7)<<3)
  __shared__ __align__(16) u16 Pb[8][512];  // per-wave P[16][32], idx ^ ((r&3)<<3)
  if (tid < 256) gc[tid] = gcum[(size_t)bh * 4096 + n * 256 + tid];
  {
    int s = tid & 255, e0 = (tid >> 8) * 64;
    const u16* vp = vb + (t0 + s) * 2048 + h * 128 + e0;
#pragma unroll
    for (int j = 0; j < 8; ++j) {
      u16x8 vv = *(const u16x8*)(vp + j * 8);
#pragma unroll
      for (int m = 0; m < 8; ++m) {
        int e = e0 + j * 8 + m;
        vt[(e * 256 + s) ^ ((e & 7) << 3)] = vv[m];
      }
    }
  }
  __syncthreads();
  const float scale = 0.08838834764831845f;
  u16* P = Pb[w];
  const f32x4 z4 = {0.f, 0.f, 0.f, 0.f};
  f32x4 acc[2][8];
#pragma unroll
  for (int i = 0; i < 2; ++i)
#pragma unroll
    for (int j = 0; j < 8; ++j) acc[i][j] = z4;
  int r0s[2], nsbs[2];
  r0s[0] = w * 16;        nsbs[0] = (w + 2) >> 1;
  r0s[1] = (15 - w) * 16; nsbs[1] = 8 - (w >> 1);
#pragma unroll
  for (int rb = 0; rb < 2; ++rb) {
    int r0 = r0s[rb], nsb = nsbs[rb];
    bf16x8 qa[4];
    {
      const u16* qp = qb + (t0 + r0 + l15) * 2048 + h * 128 + l4 * 8;
#pragma unroll
      for (int ks = 0; ks < 4; ++ks) qa[ks] = *(const bf16x8*)(qp + ks * 32);
    }
    for (int sbk = 0; sbk < nsb; ++sbk) {
      int s0 = sbk * 32;
      f32x4 sc[2] = {z4, z4};
#pragma unroll
      for (int cf = 0; cf < 2; ++cf) {
        const u16* kp = kb + (t0 + s0 + cf * 16 + l15) * 2048 + h * 128 + l4 * 8;
#pragma unroll
        for (int ks = 0; ks < 4; ++ks)
          sc[cf] = mfma16(qa[ks], *(const bf16x8*)(kp + ks * 32), sc[cf]);
      }
#pragma unroll
      for (int cf = 0; cf < 2; ++cf) {
        int s = s0 + cf * 16 + l15;
        float gs = gc[s];
#pragma unroll
        for (int reg = 0; reg < 4; ++reg) {
          int rl = l4 * 4 + reg;
          int r = r0 + rl;
          float val = (r >= s) ? sc[cf][reg] * scale * __expf(gc[r] - gs) : 0.f;
          P[(rl * 32 + cf * 16 + l15) ^ ((rl & 3) << 3)] = f2bf(val);
        }
      }
      bf16x8 pa = *(const bf16x8*)(P + ((l15 * 32 + l4 * 8) ^ ((l15 & 3) << 3)));
#pragma unroll
      for (int bc = 0; bc < 8; ++bc) {
        int e = bc * 16 + l15;
        bf16x8 vf = *(const bf16x8*)(vt + ((e * 256 + s0 + l4 * 8) ^ ((e & 7) << 3)));
        acc[rb][bc] = mfma16(pa, vf, acc[rb][bc]);
      }
    }
  }
  size_t sbase = ((size_t)bh * 16 + n) * 16384;
#pragma unroll
  for (int rb = 0; rb < 2; ++rb) {
    int r0 = r0s[rb];
    float qd = __expf(gc[r0 + l15]);
#pragma unroll
    for (int ks = 0; ks < 4; ++ks) {
      u16x8 qu = *(const u16x8*)(qb + (t0 + r0 + l15) * 2048 + h * 128 + ks * 32 + l4 * 8);
      u16x8 ru;
#pragma unroll
      for (int m = 0; m < 8; ++m) ru[m] = f2bf(bf2f(qu[m]) * qd);
      bf16x8 pa2 = __builtin_bit_cast(bf16x8, ru);
#pragma unroll
      for (int bc = 0; bc < 8; ++bc) {
        int e = bc * 16 + l15;
        bf16x8 sf = *(const bf16x8*)(S_T + sbase + (size_t)e * 128 + ks * 32 + l4 * 8);
        acc[rb][bc] = mfma16(pa2, sf, acc[rb][bc]);
      }
    }
  }
#pragma unroll
  for (int rb = 0; rb < 2; ++rb) {
    int r0 = r0s[rb];
#pragma unroll
    for (int reg = 0; reg < 4; ++reg) {
      float ss = 0.f;
#pragma unroll
      for (int bc = 0; bc < 8; ++bc) { float v = acc[rb][bc][reg]; ss += v * v; }
      ss += __shfl_xor(ss, 1);
      ss += __shfl_xor(ss, 2);
      ss += __shfl_xor(ss, 4);
      ss += __shfl_xor(ss, 8);
      float rinv = rsqrtf(ss * 0.0078125f + 1e-5f);
      int r = r0 + l4 * 4 + reg;
      size_t rowoff = (t0 + r) * 2048 + h * 128;
#pragma unroll
      for (int bc = 0; bc < 8; ++bc) {
        int e = bc * 16 + l15;
        float gval = bf2f(gbuf[rowoff + e]);
        float sig = 1.f / (1.f + __expf(-gval));
        ob[rowoff + e] = f2bf(acc[rb][bc][reg] * rinv * gval * sig);
      }
    }
  }
}

extern "C" void kernel_launch(void* const* d_in, const int* in_sizes, int n_in,
                              void* d_out, int out_size, void* d_ws, size_t ws_size,
                              hipStream_t stream) {
  const float* x    = (const float*)d_in[0];
  const float* cosT = (const float*)d_in[1];
  const float* sinT = (const float*)d_in[2];
  const float* Wq   = (const float*)d_in[3];
  const float* Wk   = (const float*)d_in[4];
  const float* Wv   = (const float*)d_in[5];
  const float* Wg   = (const float*)d_in[6];
  const float* Wgt  = (const float*)d_in[7];
  const float* Wout = (const float*)d_in[8];
  float* out = (float*)d_out;

  const size_t MB32 = (size_t)33554432;
  const size_t W8   = (size_t)8388608;
  char* ws = (char*)d_ws;
  size_t need = MB32 + 5 * W8 + 4 * MB32 + 2 * (size_t)524288;
  if (ws_size < need) return;

  u16*   xb    = (u16*)(ws);
  float* SinT  = (float*)(ws);
  u16*   ob    = (u16*)(ws);
  u16*   WqT   = (u16*)(ws + MB32);          // WqT..WgT,WoutT contiguous (5x 2048^2 bf16)
  u16*   S_T   = (u16*)(ws + MB32);          // overlays WqT+WkT after projections
  u16*   WoutT = (u16*)(ws + MB32 + 4 * W8);
  u16*   qb    = (u16*)(ws + MB32 + 5 * W8); // qb,kb,vb,gb contiguous 4x32MB
  u16*   kb    = qb + 16777216;
  u16*   vb    = qb + 2 * 16777216;
  u16*   gb    = qb + 3 * (size_t)16777216;
  float* gt    = (float*)(ws + MB32 + 5 * W8 + 4 * MB32);
  float* gcum  = (float*)(ws + MB32 + 5 * W8 + 4 * MB32 + 524288);

  k_gtcast<<<2048, 256, 0, stream>>>(x, Wgt, xb, gt);
  k_wtrans5<<<dim3(32, 32, 5), 256, 0, stream>>>(Wq, Wk, Wv, Wg, Wout, WqT);

  // fused q/k/v/g projection with RoPE fused into the epilogue for q,k
  k_gemm2<2><<<1024, 512, 0, stream>>>(xb, WqT, qb, 8192, 8192, 2048, cosT, sinT);

  k_cumsum<<<dim3(16, 32), 256, 0, stream>>>(gt, gcum);
  k_sin<<<dim3(16, 32), 256, 0, stream>>>(kb, vb, gcum, SinT);
  k_state<<<256, 256, 0, stream>>>(SinT, gcum, S_T);
  k_attn<<<dim3(16, 32), 512, 0, stream>>>(qb, kb, vb, gb, gcum, S_T, ob);
  k_gemm2<1><<<256, 512, 0, stream>>>(ob, WoutT, out, 8192, 2048, 2048, nullptr, nullptr);
}

// Round 18
// 492.882 us; speedup vs baseline: 1.0136x; 1.0014x over previous
//
#include <hip/hip_runtime.h>

typedef unsigned short u16;
typedef short bf16x8 __attribute__((ext_vector_type(8)));
typedef unsigned short u16x8 __attribute__((ext_vector_type(8)));
typedef unsigned short u16x4 __attribute__((ext_vector_type(4)));
typedef float f32x4 __attribute__((ext_vector_type(4)));

typedef __attribute__((address_space(1))) void* gas_ptr;
typedef __attribute__((address_space(3))) void* las_ptr;

__device__ __forceinline__ float bf2f(u16 v) {
  unsigned u = ((unsigned)v) << 16;
  return __builtin_bit_cast(float, u);
}
__device__ __forceinline__ u16 f2bf(float f) {
  unsigned u = __builtin_bit_cast(unsigned, f);
  u += 0x7fffu + ((u >> 16) & 1u);
  return (u16)(u >> 16);
}
__device__ __forceinline__ f32x4 mfma16(bf16x8 a, bf16x8 b, f32x4 c) {
  return __builtin_amdgcn_mfma_f32_16x16x32_bf16(a, b, c, 0, 0, 0);
}
__device__ __forceinline__ void gload_lds16(const void* g, void* l) {
  __builtin_amdgcn_global_load_lds((gas_ptr)g, (las_ptr)l, 16, 0, 0);
}

#define SB __builtin_amdgcn_sched_barrier(0)
#define BAR do { SB; __builtin_amdgcn_s_barrier(); SB; } while (0)

// ------ fused: gt = logsigmoid(x@Wgt)/16 AND xb = bf16(x); 4 tokens/block ------
__global__ __launch_bounds__(256) void k_gtcast(const float* __restrict__ x,
                                                const float* __restrict__ Wgt,
                                                u16* __restrict__ xb,
                                                float* __restrict__ gt) {
  int t0 = blockIdx.x * 4;
  int tid = threadIdx.x;
  __shared__ __align__(16) float xs[4][2048];
#pragma unroll
  for (int tok = 0; tok < 4; ++tok) {
    size_t rb = (size_t)(t0 + tok) * 2048;
#pragma unroll
    for (int i = 0; i < 8; ++i) {
      int idx = tid + i * 256;
      float v = x[rb + idx];
      xs[tok][idx] = v;
      xb[rb + idx] = f2bf(v);
    }
  }
  __syncthreads();
  int head = tid & 15, ks = tid >> 4;
  float p0 = 0.f, p1 = 0.f, p2 = 0.f, p3 = 0.f;
  for (int i = 0; i < 128; ++i) {
    int k = ks + i * 16;
    float wv = Wgt[k * 16 + head];
    p0 += xs[0][k] * wv;
    p1 += xs[1][k] * wv;
    p2 += xs[2][k] * wv;
    p3 += xs[3][k] * wv;
  }
  __shared__ float ps[4][16][17];
  ps[0][ks][head] = p0;
  ps[1][ks][head] = p1;
  ps[2][ks][head] = p2;
  ps[3][ks][head] = p3;
  __syncthreads();
  if (tid < 64) {
    int tok = tid >> 4, hh = tid & 15;
    float z = 0.f;
#pragma unroll
    for (int j = 0; j < 16; ++j) z += ps[tok][j][hh];
    float lsz = (z >= 0.f) ? -log1pf(__expf(-z)) : (z - log1pf(__expf(z)));
    int t = t0 + tok;
    int b = t >> 12, tl = t & 4095;
    gt[((size_t)(b * 16 + hh)) * 4096 + tl] = lsz * 0.0625f;
  }
}

// ------ weight transpose+cast, 5 matrices in one launch (dest contiguous) ------
__global__ __launch_bounds__(256) void k_wtrans5(const float* __restrict__ W0,
                                                 const float* __restrict__ W1,
                                                 const float* __restrict__ W2,
                                                 const float* __restrict__ W3,
                                                 const float* __restrict__ W4,
                                                 u16* __restrict__ WT) {
  const int K = 2048, N = 2048;
  int z = blockIdx.z;
  const float* W = (z == 0) ? W0 : (z == 1) ? W1 : (z == 2) ? W2 : (z == 3) ? W3 : W4;
  u16* dst = WT + (size_t)z * 4194304;
  int n0 = blockIdx.x * 64, k0 = blockIdx.y * 64;
  int tid = threadIdx.x;
  __shared__ __align__(16) float tf[64][68];
  int r = tid >> 4, c4 = (tid & 15) * 4;
#pragma unroll
  for (int i = 0; i < 4; ++i) {
    int row = r + i * 16;
    f32x4 v = *(const f32x4*)(W + (size_t)(k0 + row) * N + n0 + c4);
    *(f32x4*)&tf[row][c4] = v;
  }
  __syncthreads();
#pragma unroll
  for (int i = 0; i < 2; ++i) {
    int chunk = tid + i * 256;
    int nl = chunk >> 3, c8 = (chunk & 7) * 8;
    u16x8 o;
#pragma unroll
    for (int m = 0; m < 8; ++m) o[m] = f2bf(tf[c8 + m][nl]);
    *(u16x8*)(dst + (size_t)(n0 + nl) * K + k0 + c8) = o;
  }
}

// ============ 256x256 GEMM, read-pipelined 4-phase (best R6 schedule) ============
// MODE 1: f32 out row-stride N.
// MODE 2: bf16 out split into 4 [M][2048] bufs by col>>11; RoPE fused for bufs 0,1
//         with cos/sin staged into the dead Al/Bl LDS post-K-loop.
template <int MODE>
__global__ __launch_bounds__(512, 2) void k_gemm2(const u16* __restrict__ A,
                                                  const u16* __restrict__ Bt,
                                                  void* __restrict__ Cp, int M, int N, int K,
                                                  const float* __restrict__ cosT,
                                                  const float* __restrict__ sinT) {
  __shared__ __align__(16) u16 Al[2][2][8192];  // [buf][half][128*64] st_16x32-swizzled
  __shared__ __align__(16) u16 Bl[2][2][8192];
  int tid = threadIdx.x, w = tid >> 6, lane = tid & 63, l15 = lane & 15, l4 = lane >> 4;
  int wm = w >> 2, wn = w & 3;
  // bijective XCD swizzle + 4x4 supertile walk (needs nwg%8==0, nbx%4==0, nby%4==0)
  int nwg = gridDim.x, bid = blockIdx.x;
  int q8 = nwg >> 3;
  int wg = (bid & 7) * q8 + (bid >> 3);
  int nbx = N >> 8;
  int nstx = nbx >> 2;
  int st = wg >> 4, r16 = wg & 15;
  int sm = st / nstx, sn = st - sm * nstx;
  int m0 = ((sm << 2) + (r16 >> 2)) << 8;
  int n0 = ((sn << 2) + (r16 & 3)) << 8;
  // staging coords: linear LDS slot -> (r,c) via inverse st_16x32 swizzle
  int rA0, rA1, rB0, rB1, cc0, cc1;
  {
    int rr[2], cch[2];
#pragma unroll
    for (int q = 0; q < 2; ++q) {
      int L = (q * 512 + tid) * 16;
      int sub = L >> 10, inner = L & 1023;
      inner ^= ((inner >> 9) & 1) << 5;
      rr[q] = ((sub >> 1) << 4) + (inner >> 6);
      cch[q] = ((sub & 1) << 5) + ((inner & 63) >> 1);
    }
    rA0 = ((rr[0] >> 6) << 7) + (rr[0] & 63);
    rA1 = ((rr[1] >> 6) << 7) + (rr[1] & 63);
    rB0 = ((rr[0] >> 5) << 6) + (rr[0] & 31);
    rB1 = ((rr[1] >> 5) << 6) + (rr[1] & 31);
    cc0 = cch[0]; cc1 = cch[1];
  }
  int innerA = ((l15 << 6) + (l4 << 4)) ^ ((l15 & 8) << 2);  // swizzled read offset (bytes)
  int ldsW = w << 9;  // wave-uniform element base for staging (q=0)

#define STAGE_A(t, h)                                                                   \
  do {                                                                                  \
    int b_ = (t) & 1;                                                                   \
    gload_lds16(A + (size_t)(m0 + rA0 + (h) * 64) * K + (t) * 64 + cc0, &Al[b_][h][ldsW]); \
    gload_lds16(A + (size_t)(m0 + rA1 + (h) * 64) * K + (t) * 64 + cc1, &Al[b_][h][4096 + ldsW]); \
  } while (0)
#define STAGE_B(t, h)                                                                   \
  do {                                                                                  \
    int b_ = (t) & 1;                                                                   \
    gload_lds16(Bt + (size_t)(n0 + rB0 + (h) * 32) * K + (t) * 64 + cc0, &Bl[b_][h][ldsW]); \
    gload_lds16(Bt + (size_t)(n0 + rB1 + (h) * 32) * K + (t) * 64 + cc1, &Bl[b_][h][4096 + ldsW]); \
  } while (0)

  const f32x4 z4 = {0.f, 0.f, 0.f, 0.f};
  f32x4 acc[8][4];
#pragma unroll
  for (int i = 0; i < 8; ++i)
#pragma unroll
    for (int j = 0; j < 4; ++j) acc[i][j] = z4;
  // four independent fragment register sets (pipelined one phase ahead)
  bf16x8 af0[4][2], af1[4][2], bf0[2][2], bf1[2][2];

#define LDA0(buf)                                                                        \
  do {                                                                                   \
    const char* Ab = (const char*)&Al[buf][0][0];                                        \
    _Pragma("unroll") for (int fi = 0; fi < 4; ++fi) _Pragma("unroll") for (int ks = 0; ks < 2; ++ks) \
        af0[fi][ks] = *(const bf16x8*)(Ab + (((wm * 4 + fi) * 2 + ks) << 10) + innerA);  \
  } while (0)
#define LDA1(buf)                                                                        \
  do {                                                                                   \
    const char* Ab = (const char*)&Al[buf][1][0];                                        \
    _Pragma("unroll") for (int fi = 0; fi < 4; ++fi) _Pragma("unroll") for (int ks = 0; ks < 2; ++ks) \
        af1[fi][ks] = *(const bf16x8*)(Ab + (((wm * 4 + fi) * 2 + ks) << 10) + innerA);  \
  } while (0)
#define LDB0(buf)                                                                        \
  do {                                                                                   \
    const char* Bb = (const char*)&Bl[buf][0][0];                                        \
    _Pragma("unroll") for (int fj = 0; fj < 2; ++fj) _Pragma("unroll") for (int ks = 0; ks < 2; ++ks) \
        bf0[fj][ks] = *(const bf16x8*)(Bb + (((wn * 2 + fj) * 2 + ks) << 10) + innerA);  \
  } while (0)
#define LDB1(buf)                                                                        \
  do {                                                                                   \
    const char* Bb = (const char*)&Bl[buf][1][0];                                        \
    _Pragma("unroll") for (int fj = 0; fj < 2; ++fj) _Pragma("unroll") for (int ks = 0; ks < 2; ++ks) \
        bf1[fj][ks] = *(const bf16x8*)(Bb + (((wn * 2 + fj) * 2 + ks) << 10) + innerA);  \
  } while (0)
#define MM(hm, hn, AF, BF)                                                               \
  do {                                                                                   \
    __builtin_amdgcn_s_setprio(1);                                                       \
    _Pragma("unroll") for (int fi = 0; fi < 4; ++fi) _Pragma("unroll") for (int fj = 0; fj < 2; ++fj) \
        _Pragma("unroll") for (int ks = 0; ks < 2; ++ks)                                 \
            acc[(hm) * 4 + fi][(hn) * 2 + fj] =                                          \
                mfma16(AF[fi][ks], BF[fj][ks], acc[(hm) * 4 + fi][(hn) * 2 + fj]);       \
    __builtin_amdgcn_s_setprio(0);                                                       \
  } while (0)

  int nt = K >> 6;
  // prologue: stage tile0 (both halves) + tile1 h0; land tile0; preload h0 frags.
  STAGE_A(0, 0); STAGE_B(0, 0); STAGE_A(0, 1); STAGE_B(0, 1);
  if (nt > 1) {
    STAGE_A(1, 0); STAGE_B(1, 0);
    asm volatile("s_waitcnt vmcnt(4)" ::: "memory");
  } else {
    asm volatile("s_waitcnt vmcnt(0)" ::: "memory");
  }
  SB;
  BAR;
  LDA0(0); LDB0(0);  // 12 ds_reads; retired by t=0 P1's lgkmcnt(4)
  // Pipeline invariants (audited steady + t=0 + tails) — the R6 best schedule:
  //  P1 lgkm(4): keeps bf1's 4 reads, retires prev-P4/prologue 12
  //  P2 lgkm(8): keeps af1's 8, retires bf1's 4
  //  P3 lgkm(0): retires af1; ONE vmcnt gate/tile keeps 3 newest stage-pairs
  //  P4: no waits; reads next-tile h0 frags after the gate+BAR
  for (int t = 0; t < nt; ++t) {
    int cur = t & 1, nxt = cur ^ 1;
    // P1: MFMA(0,0) = af0 x bf0; read bf1; stage B(t+1,h1)
    LDB1(cur);
    if (t + 1 < nt) STAGE_B(t + 1, 1);
    asm volatile("s_waitcnt lgkmcnt(4)" ::: "memory"); SB;
    MM(0, 0, af0, bf0);
    BAR;
    // P2: MFMA(0,1) = af0 x bf1; read af1; stage A(t+1,h1)
    LDA1(cur);
    if (t + 1 < nt) STAGE_A(t + 1, 1);
    asm volatile("s_waitcnt lgkmcnt(8)" ::: "memory"); SB;
    MM(0, 1, af0, bf1);
    BAR;
    // P3: MFMA(1,0) = af1 x bf0; stage A(t+2,h0); per-tile vmcnt gate
    if (t + 2 < nt) STAGE_A(t + 2, 0);
    asm volatile("s_waitcnt lgkmcnt(0)" ::: "memory"); SB;
    MM(1, 0, af1, bf0);
    if (t + 1 < nt) {
      if (t + 2 < nt) { asm volatile("s_waitcnt vmcnt(6)" ::: "memory"); }
      else            { asm volatile("s_waitcnt vmcnt(4)" ::: "memory"); }
    } else            { asm volatile("s_waitcnt vmcnt(0)" ::: "memory"); }
    SB;
    BAR;
    // P4: MFMA(1,1) = af1 x bf1; read next-tile h0 frags; stage B(t+2,h0); NO waits
    if (t + 1 < nt) { LDA0(nxt); LDB0(nxt); }
    if (t + 2 < nt) STAGE_B(t + 2, 0);
    MM(1, 1, af1, bf1);
    BAR;
  }
  asm volatile("s_waitcnt lgkmcnt(0)" ::: "memory");
  asm volatile("s_waitcnt vmcnt(0)" ::: "memory");  // drain DMAs before LDS reuse
#undef STAGE_A
#undef STAGE_B
#undef LDA0
#undef LDA1
#undef LDB0
#undef LDB1
#undef MM
  // ---- epilogue ----
  if (MODE == 2) {
    // Reuse dead Al/Bl as cos/sin row cache: rows tl0..tl0+255, 64 f32 each.
    // (4096 % 256 == 0 so a 256-row tile never straddles the batch boundary.)
    float* cosL = (float*)&Al[0][0][0];  // 64 KB = 256*64 f32
    float* sinL = (float*)&Bl[0][0][0];
    __syncthreads();  // all waves done reading Al/Bl (per-wave lgkm drained above)
    int tl0 = m0 & 4095;
#pragma unroll
    for (int i = 0; i < 8; ++i) {
      int idx = tid + i * 512;  // [0,4096) f32x4 chunks
      int rr_ = idx >> 4, c4_ = (idx & 15) * 4;
      *(f32x4*)&cosL[rr_ * 64 + c4_] = *(const f32x4*)(cosT + (size_t)(tl0 + rr_) * 64 + c4_);
      *(f32x4*)&sinL[rr_ * 64 + c4_] = *(const f32x4*)(sinT + (size_t)(tl0 + rr_) * 64 + c4_);
    }
    __syncthreads();
#pragma unroll
    for (int fi = 0; fi < 8; ++fi)
#pragma unroll
      for (int fj = 0; fj < 4; ++fj) {
        int rloc = wm * 128 + fi * 16 + l4 * 4;
        int row0 = m0 + rloc;
        int col = n0 + wn * 64 + fj * 16 + l15;
        int bufi = col >> 11;
        u16* C = (u16*)Cp + (size_t)bufi * 16777216 + (col & 2047);
        if (bufi < 2) {  // q or k: interleaved RoPE from LDS tables (wave-uniform branch)
          int i0 = (col & 127) >> 1;
          bool evenc = (col & 1) == 0;
#pragma unroll
          for (int reg = 0; reg < 4; ++reg) {
            float cv = cosL[(rloc + reg) * 64 + i0];
            float sv = sinL[(rloc + reg) * 64 + i0];
            float v = acc[fi][fj][reg];
            float partner = __shfl_xor(v, 1);
            float r = evenc ? (v * cv - partner * sv) : (partner * sv + v * cv);
            C[(size_t)(row0 + reg) * 2048] = f2bf(r);
          }
        } else {
#pragma unroll
          for (int reg = 0; reg < 4; ++reg) C[(size_t)(row0 + reg) * 2048] = f2bf(acc[fi][fj][reg]);
        }
      }
  } else {
#pragma unroll
    for (int fi = 0; fi < 8; ++fi)
#pragma unroll
      for (int fj = 0; fj < 4; ++fj) {
        int row0 = m0 + wm * 128 + fi * 16 + l4 * 4;
        int col = n0 + wn * 64 + fj * 16 + l15;
        float* C = (float*)Cp;
#pragma unroll
        for (int reg = 0; reg < 4; ++reg) C[(size_t)(row0 + reg) * N + col] = acc[fi][fj][reg];
      }
  }
}

// ---------------- per-chunk inclusive cumsum over 256 ----------------
__global__ void k_cumsum(const float* __restrict__ gt, float* __restrict__ gcum) {
  int n = blockIdx.x, bh = blockIdx.y, c = threadIdx.x;
  __shared__ float s[256];
  size_t base = (size_t)bh * 4096 + n * 256;
  s[c] = gt[base + c];
  __syncthreads();
  for (int off = 1; off < 256; off <<= 1) {
    float t = (c >= off) ? s[c - off] : 0.f;
    __syncthreads();
    s[c] += t;
    __syncthreads();
  }
  gcum[base + c] = s[c];
}

// ---------------- S_in^T[e][d] = sum_c (k[c,d]*kdec[c]*scale) * v[c,e], per (bh,n) ----------------
__global__ __launch_bounds__(256) void k_sin(const u16* __restrict__ kb, const u16* __restrict__ vb,
                                             const float* __restrict__ gcum, float* __restrict__ SinT) {
  int n = blockIdx.x, bh = blockIdx.y;
  int b = bh >> 4, h = bh & 15;
  int tid = threadIdx.x, w = tid >> 6, lane = tid & 63, l15 = lane & 15, l4 = lane >> 4;
  size_t t0 = (size_t)b * 4096 + n * 256;
  __shared__ float gc[256];
  __shared__ __align__(16) u16 kt[128 * 72];
  __shared__ __align__(16) u16 vt[128 * 72];
  gc[tid] = gcum[(size_t)bh * 4096 + n * 256 + tid];
  __syncthreads();
  float gtot = gc[255];
  const float scale = 0.08838834764831845f;
  const f32x4 z4 = {0.f, 0.f, 0.f, 0.f};
  f32x4 acc[2][8];
#pragma unroll
  for (int i = 0; i < 2; ++i)
#pragma unroll
    for (int j = 0; j < 8; ++j) acc[i][j] = z4;
  int cl = tid >> 2, fq = (tid & 3) * 32;
  for (int c0 = 0; c0 < 256; c0 += 64) {
    __syncthreads();
    float kd = __expf(gtot - gc[c0 + cl]) * scale;
    const u16* kp = kb + (t0 + c0 + cl) * 2048 + h * 128 + fq;
    const u16* vp = vb + (t0 + c0 + cl) * 2048 + h * 128 + fq;
#pragma unroll
    for (int jj = 0; jj < 4; ++jj) {
      u16x8 kv = *(const u16x8*)(kp + jj * 8);
      u16x8 vv = *(const u16x8*)(vp + jj * 8);
#pragma unroll
      for (int m = 0; m < 8; ++m) {
        int f = fq + jj * 8 + m;
        kt[f * 72 + cl] = f2bf(bf2f(kv[m]) * kd);
        vt[f * 72 + cl] = vv[m];
      }
    }
    __syncthreads();
#pragma unroll
    for (int ks = 0; ks < 2; ++ks) {
      int coff = ks * 32 + l4 * 8;
      bf16x8 bfr[8];
#pragma unroll
      for (int bc = 0; bc < 8; ++bc) bfr[bc] = *(const bf16x8*)(vt + (bc * 16 + l15) * 72 + coff);
#pragma unroll
      for (int ar = 0; ar < 2; ++ar) {
        bf16x8 afr = *(const bf16x8*)(kt + (w * 32 + ar * 16 + l15) * 72 + coff);
#pragma unroll
        for (int bc = 0; bc < 8; ++bc) acc[ar][bc] = mfma16(afr, bfr[bc], acc[ar][bc]);
      }
    }
  }
  size_t sbo = ((size_t)bh * 16 + n) * 16384;
#pragma unroll
  for (int ar = 0; ar < 2; ++ar) {
    int d = w * 32 + ar * 16 + l4 * 4;
#pragma unroll
    for (int bc = 0; bc < 8; ++bc) {
      int e = bc * 16 + l15;
      *(f32x4*)(SinT + sbo + (size_t)e * 128 + d) = acc[ar][bc];
    }
  }
}

// ---------------- recurrence: S_T[bh,n] (bf16, [e][d]) = state before chunk n ----------------
__global__ void k_state(const float* __restrict__ SinT, const float* __restrict__ gcum,
                        u16* __restrict__ S_T) {
  int bh = blockIdx.x >> 3, sl = blockIdx.x & 7;
  int base_l = sl * 2048 + threadIdx.x;
  float S[8];
#pragma unroll
  for (int i = 0; i < 8; ++i) S[i] = 0.f;
  for (int nn = 0; nn < 16; ++nn) {
    size_t tb = ((size_t)bh * 16 + nn) * 16384;
#pragma unroll
    for (int i = 0; i < 8; ++i) S_T[tb + base_l + i * 256] = f2bf(S[i]);
    float cd = __expf(gcum[(size_t)bh * 4096 + nn * 256 + 255]);
#pragma unroll
    for (int i = 0; i < 8; ++i) S[i] = S[i] * cd + SinT[tb + base_l + i * 256];
  }
}

// ---------------- fused attention: balanced 8-wave version ----------------
__global__ __launch_bounds__(512, 4) void k_attn(
    const u16* __restrict__ qb, const u16* __restrict__ kb, const u16* __restrict__ vb,
    const u16* __restrict__ gbuf, const float* __restrict__ gcum,
    const u16* __restrict__ S_T, u16* __restrict__ ob) {
  int n = blockIdx.x, bh = blockIdx.y;
  int b = bh >> 4, h = bh & 15;
  int tid = threadIdx.x, w = tid >> 6, lane = tid & 63, l15 = lane & 15, l4 = lane >> 4;
  size_t t0 = (size_t)b * 4096 + n * 256;
  __shared__ float gc[256];
  __shared__ __align__(16) u16 vt[32768];   // V^T[e][s], idx ^ ((e&7)<<3)
  __shared__ __align__(16) u16 Pb[8][512];  // per-wave P[16][32], idx ^ ((r&3)<<3)
  if (tid < 256) gc[tid] = gcum[(size_t)bh * 4096 + n * 256 + tid];
  {
    int s = tid & 255, e0 = (tid >> 8) * 64;
    const u16* vp = vb + (t0 + s) * 2048 + h * 128 + e0;
#pragma unroll
    for (int j = 0; j < 8; ++j) {
      u16x8 vv = *(const u16x8*)(vp + j * 8);
#pragma unroll
      for (int m = 0; m < 8; ++m) {
        int e = e0 + j * 8 + m;
        vt[(e * 256 + s) ^ ((e & 7) << 3)] = vv[m];
      }
    }
  }
  __syncthreads();
  const float scale = 0.08838834764831845f;
  u16* P = Pb[w];
  const f32x4 z4 = {0.f, 0.f, 0.f, 0.f};
  f32x4 acc[2][8];
#pragma unroll
  for (int i = 0; i < 2; ++i)
#pragma unroll
    for (int j = 0; j < 8; ++j) acc[i][j] = z4;
  int r0s[2], nsbs[2];
  r0s[0] = w * 16;        nsbs[0] = (w + 2) >> 1;
  r0s[1] = (15 - w) * 16; nsbs[1] = 8 - (w >> 1);
#pragma unroll
  for (int rb = 0; rb < 2; ++rb) {
    int r0 = r0s[rb], nsb = nsbs[rb];
    bf16x8 qa[4];
    {
      const u16* qp = qb + (t0 + r0 + l15) * 2048 + h * 128 + l4 * 8;
#pragma unroll
      for (int ks = 0; ks < 4; ++ks) qa[ks] = *(const bf16x8*)(qp + ks * 32);
    }
    for (int sbk = 0; sbk < nsb; ++sbk) {
      int s0 = sbk * 32;
      f32x4 sc[2] = {z4, z4};
#pragma unroll
      for (int cf = 0; cf < 2; ++cf) {
        const u16* kp = kb + (t0 + s0 + cf * 16 + l15) * 2048 + h * 128 + l4 * 8;
#pragma unroll
        for (int ks = 0; ks < 4; ++ks)
          sc[cf] = mfma16(qa[ks], *(const bf16x8*)(kp + ks * 32), sc[cf]);
      }
#pragma unroll
      for (int cf = 0; cf < 2; ++cf) {
        int s = s0 + cf * 16 + l15;
        float gs = gc[s];
#pragma unroll
        for (int reg = 0; reg < 4; ++reg) {
          int rl = l4 * 4 + reg;
          int r = r0 + rl;
          float val = (r >= s) ? sc[cf][reg] * scale * __expf(gc[r] - gs) : 0.f;
          P[(rl * 32 + cf * 16 + l15) ^ ((rl & 3) << 3)] = f2bf(val);
        }
      }
      bf16x8 pa = *(const bf16x8*)(P + ((l15 * 32 + l4 * 8) ^ ((l15 & 3) << 3)));
#pragma unroll
      for (int bc = 0; bc < 8; ++bc) {
        int e = bc * 16 + l15;
        bf16x8 vf = *(const bf16x8*)(vt + ((e * 256 + s0 + l4 * 8) ^ ((e & 7) << 3)));
        acc[rb][bc] = mfma16(pa, vf, acc[rb][bc]);
      }
    }
  }
  size_t sbase = ((size_t)bh * 16 + n) * 16384;
#pragma unroll
  for (int rb = 0; rb < 2; ++rb) {
    int r0 = r0s[rb];
    float qd = __expf(gc[r0 + l15]);
#pragma unroll
    for (int ks = 0; ks < 4; ++ks) {
      u16x8 qu = *(const u16x8*)(qb + (t0 + r0 + l15) * 2048 + h * 128 + ks * 32 + l4 * 8);
      u16x8 ru;
#pragma unroll
      for (int m = 0; m < 8; ++m) ru[m] = f2bf(bf2f(qu[m]) * qd);
      bf16x8 pa2 = __builtin_bit_cast(bf16x8, ru);
#pragma unroll
      for (int bc = 0; bc < 8; ++bc) {
        int e = bc * 16 + l15;
        bf16x8 sf = *(const bf16x8*)(S_T + sbase + (size_t)e * 128 + ks * 32 + l4 * 8);
        acc[rb][bc] = mfma16(pa2, sf, acc[rb][bc]);
      }
    }
  }
#pragma unroll
  for (int rb = 0; rb < 2; ++rb) {
    int r0 = r0s[rb];
#pragma unroll
    for (int reg = 0; reg < 4; ++reg) {
      float ss = 0.f;
#pragma unroll
      for (int bc = 0; bc < 8; ++bc) { float v = acc[rb][bc][reg]; ss += v * v; }
      ss += __shfl_xor(ss, 1);
      ss += __shfl_xor(ss, 2);
      ss += __shfl_xor(ss, 4);
      ss += __shfl_xor(ss, 8);
      float rinv = rsqrtf(ss * 0.0078125f + 1e-5f);
      int r = r0 + l4 * 4 + reg;
      size_t rowoff = (t0 + r) * 2048 + h * 128;
#pragma unroll
      for (int bc = 0; bc < 8; ++bc) {
        int e = bc * 16 + l15;
        float gval = bf2f(gbuf[rowoff + e]);
        float sig = 1.f / (1.f + __expf(-gval));
        ob[rowoff + e] = f2bf(acc[rb][bc][reg] * rinv * gval * sig);
      }
    }
  }
}

extern "C" void kernel_launch(void* const* d_in, const int* in_sizes, int n_in,
                              void* d_out, int out_size, void* d_ws, size_t ws_size,
                              hipStream_t stream) {
  const float* x    = (const float*)d_in[0];
  const float* cosT = (const float*)d_in[1];
  const float* sinT = (const float*)d_in[2];
  const float* Wq   = (const float*)d_in[3];
  const float* Wk   = (const float*)d_in[4];
  const float* Wv   = (const float*)d_in[5];
  const float* Wg   = (const float*)d_in[6];
  const float* Wgt  = (const float*)d_in[7];
  const float* Wout = (const float*)d_in[8];
  float* out = (float*)d_out;

  const size_t MB32 = (size_t)33554432;
  const size_t W8   = (size_t)8388608;
  char* ws = (char*)d_ws;
  size_t need = MB32 + 5 * W8 + 4 * MB32 + 2 * (size_t)524288;
  if (ws_size < need) return;

  u16*   xb    = (u16*)(ws);
  float* SinT  = (float*)(ws);
  u16*   ob    = (u16*)(ws);
  u16*   WqT   = (u16*)(ws + MB32);          // WqT..WgT,WoutT contiguous (5x 2048^2 bf16)
  u16*   S_T   = (u16*)(ws + MB32);          // overlays WqT+WkT after projections
  u16*   WoutT = (u16*)(ws + MB32 + 4 * W8);
  u16*   qb    = (u16*)(ws + MB32 + 5 * W8); // qb,kb,vb,gb contiguous 4x32MB
  u16*   kb    = qb + 16777216;
  u16*   vb    = qb + 2 * 16777216;
  u16*   gb    = qb + 3 * (size_t)16777216;
  float* gt    = (float*)(ws + MB32 + 5 * W8 + 4 * MB32);
  float* gcum  = (float*)(ws + MB32 + 5 * W8 + 4 * MB32 + 524288);

  k_gtcast<<<2048, 256, 0, stream>>>(x, Wgt, xb, gt);
  k_wtrans5<<<dim3(32, 32, 5), 256, 0, stream>>>(Wq, Wk, Wv, Wg, Wout, WqT);

  // fused q/k/v/g projection with RoPE fused into the epilogue for q,k
  k_gemm2<2><<<1024, 512, 0, stream>>>(xb, WqT, qb, 8192, 8192, 2048, cosT, sinT);

  k_cumsum<<<dim3(16, 32), 256, 0, stream>>>(gt, gcum);
  k_sin<<<dim3(16, 32), 256, 0, stream>>>(kb, vb, gcum, SinT);
  k_state<<<256, 256, 0, stream>>>(SinT, gcum, S_T);
  k_attn<<<dim3(16, 32), 512, 0, stream>>>(qb, kb, vb, gb, gcum, S_T, ob);
  k_gemm2<1><<<256, 512, 0, stream>>>(ob, WoutT, out, 8192, 2048, 2048, nullptr, nullptr);
}